// Round 4
// baseline (430.827 us; speedup 1.0000x reference)
//
#include <hip/hip_runtime.h>
#include <hip/hip_bf16.h>
#include <math.h>

// Problem constants (from reference)
#define PTOK 4096      // P
#define BDIM 4         // B
#define FULLD 4096     // FULL
#define SLICE 512
#define SL_START 1024
#define EDIM 1024
#define FP_MIN_C 0.1875f
#define FP_MAX_C 0.4375f

typedef __attribute__((ext_vector_type(8))) short bf16x8;
typedef __attribute__((ext_vector_type(4))) float f32x4;

// round-to-nearest-even f32 -> bf16 bits
__device__ __forceinline__ unsigned short f2bf(float f) {
    unsigned int u = __float_as_uint(f);
    unsigned int r = (u + 0x7fffu + ((u >> 16) & 1u)) >> 16;
    return (unsigned short)r;
}

// ---------------------------------------------------------------------------
// 1) fused prep: block 0 = fingerprint scan; blocks 1..5 = dirs normalize;
//    blocks 6..389 = weight fp32->bf16 convert
// ---------------------------------------------------------------------------
__global__ __launch_bounds__(1024) void prep_kernel(const float* __restrict__ fp,
                                                    int* __restrict__ idx,
                                                    const float* __restrict__ penta,
                                                    float* __restrict__ dirs,
                                                    const float* __restrict__ Wq,
                                                    const float* __restrict__ Wk,
                                                    const float* __restrict__ Wv,
                                                    unsigned short* __restrict__ Wb) {
    int blk = blockIdx.x;
    int t = threadIdx.x;
    if (blk == 0) {
        int m[4];
        int c = 0;
#pragma unroll
        for (int i = 0; i < 4; ++i) {
            float f = fp[t * 4 + i];
            m[i] = (f >= FP_MIN_C && f < FP_MAX_C) ? 1 : 0;
            c += m[i];
        }
        int lane = t & 63, wv = t >> 6;
        int inc = c;
#pragma unroll
        for (int off = 1; off < 64; off <<= 1) {
            int n = __shfl_up(inc, off, 64);
            if (lane >= off) inc += n;
        }
        __shared__ int wsum[16];
        if (lane == 63) wsum[wv] = inc;
        __syncthreads();
        if (t < 16) {
            int v = wsum[t];
            int in2 = v;
#pragma unroll
            for (int off = 1; off < 16; off <<= 1) {
                int n = __shfl_up(in2, off, 16);
                if (t >= off) in2 += n;
            }
            wsum[t] = in2 - v;  // exclusive wave base
        }
        __syncthreads();
        int pos = wsum[wv] + inc - c;
#pragma unroll
        for (int i = 0; i < 4; ++i) {
            if (m[i]) idx[pos++] = t * 4 + i;
        }
    } else if (blk <= 5) {
        int v = blk - 1;
        float4 p = make_float4(0.f, 0.f, 0.f, 0.f);
        float ss = 0.f;
        if (t < 256) {
            p = ((const float4*)(penta + (size_t)v * EDIM))[t];
            ss = p.x * p.x + p.y * p.y + p.z * p.z + p.w * p.w;
        }
        for (int off = 32; off > 0; off >>= 1) ss += __shfl_down(ss, off, 64);
        __shared__ float dsum[16];
        if ((t & 63) == 0) dsum[t >> 6] = ss;
        __syncthreads();
        if (t < 256) {
            float tot = dsum[0] + dsum[1] + dsum[2] + dsum[3];
            float inv = 1.0f / sqrtf(tot);
            float4 o = make_float4(p.x * inv, p.y * inv, p.z * inv, p.w * inv);
            ((float4*)(dirs + (size_t)v * EDIM))[t] = o;
        }
    } else {
        int i = (blk - 6) * 1024 + t;  // float4 index over 3*131072
        int mat = i >> 17;
        int rem = i & 131071;
        const float* src = (mat == 0) ? Wq : ((mat == 1) ? Wk : Wv);
        float4 v = ((const float4*)src)[rem];
        ushort4 o;
        o.x = f2bf(v.x); o.y = f2bf(v.y); o.z = f2bf(v.z); o.w = f2bf(v.w);
        ((ushort4*)(Wb + (size_t)mat * EDIM * SLICE))[rem] = o;
    }
}

// ---------------------------------------------------------------------------
// 2) gather + gating MLP + scale -> Ag (M x 512, bf16); 8 tokens per block
// ---------------------------------------------------------------------------
#define GT 8
__global__ __launch_bounds__(256) void gate_kernel(const float* __restrict__ tokens,
                                                   const int* __restrict__ idx,
                                                   const float* __restrict__ Wg1,
                                                   const float* __restrict__ bg1,
                                                   const float* __restrict__ Wg2,
                                                   const float* __restrict__ bg2,
                                                   const float* __restrict__ alpha,
                                                   unsigned short* __restrict__ Ag,
                                                   int Ntok, int M) {
    __shared__ float rows[GT][SLICE];   // 16 KB
    __shared__ float hred[GT][128];     // 4 KB
    __shared__ float ssc[GT];

    int tid = threadIdx.x;
    int tok0 = blockIdx.x * GT;

#pragma unroll
    for (int i = 0; i < 4; ++i) {
        int flat = i * 256 + tid;           // float4 slot
        int tk = flat >> 7, c4 = flat & 127;
        int g = tok0 + tk;
        if (g >= M) g = M - 1;
        int b = g / Ntok;
        int j = g - b * Ntok;
        int p = idx[j];
        const float4* src = (const float4*)(tokens + ((size_t)b * PTOK + p) * FULLD + SL_START);
        ((float4*)rows[tk])[c4] = src[c4];
    }
    __syncthreads();

    int hidx = tid & 127;
    int grp = tid >> 7;  // tokens grp*4 .. grp*4+3
    const float4* w4 = (const float4*)(Wg1 + (size_t)hidx * SLICE);
    float bias = bg1[hidx];
    float acc[4] = {bias, bias, bias, bias};
#pragma unroll 4
    for (int k = 0; k < SLICE / 4; ++k) {
        float4 w = w4[k];
#pragma unroll
        for (int t8 = 0; t8 < 4; ++t8) {
            float4 r = ((const float4*)rows[grp * 4 + t8])[k];
            acc[t8] += r.x * w.x + r.y * w.y + r.z * w.z + r.w * w.w;
        }
    }
    float wg2 = Wg2[hidx];
#pragma unroll
    for (int t8 = 0; t8 < 4; ++t8) {
        float a = acc[t8];
        float hg = 0.5f * a * (1.0f + erff(a * 0.70710678118654752f));
        hred[grp * 4 + t8][hidx] = hg * wg2;
    }
    __syncthreads();

    int wv = tid >> 6, l = tid & 63;
    float aw = 1.0f / (1.0f + expf(-alpha[0]));
#pragma unroll
    for (int z = 0; z < 2; ++z) {
        int tk = wv * 2 + z;
        float v = hred[tk][l] + hred[tk][l + 64];
        for (int off = 32; off > 0; off >>= 1) v += __shfl_down(v, off, 64);
        if (l == 0) {
            float logit = v + bg2[0];
            float gate = 1.0f / (1.0f + expf(-logit));
            ssc[tk] = gate * aw + (1.0f - aw);
        }
    }
    __syncthreads();

#pragma unroll
    for (int i = 0; i < 4; ++i) {
        int flat = i * 256 + tid;
        int tk = flat >> 7, c4 = flat & 127;
        int g = tok0 + tk;
        if (g < M) {
            float4 r = ((const float4*)rows[tk])[c4];
            float s = ssc[tk];
            ushort4 o;
            o.x = f2bf(r.x * s); o.y = f2bf(r.y * s);
            o.z = f2bf(r.z * s); o.w = f2bf(r.w * s);
            ((ushort4*)(Ag + (size_t)g * SLICE))[c4] = o;
        }
    }
}

// ---------------------------------------------------------------------------
// 3) MFMA bf16 GEMM, LDS-free: fragments loaded DIRECTLY from global (L2).
//    C[m,n] = sum_k A[m,k]*W[n,k]. K=512 is short; A (4MB) and W (3MB) are
//    L2-resident, so skipping LDS removes all ds_read + all barriers and
//    lets the compiler pipeline loads vs MFMA with plain vmcnt.
//    128x128 tile, 4 waves (2x2), 64x64/wave via 16x16x32, reg double-buffer.
// ---------------------------------------------------------------------------
__global__ __launch_bounds__(256) void qkv_mfma(const unsigned short* __restrict__ Ag,
                                                const unsigned short* __restrict__ Wb,
                                                float* __restrict__ out, int M) {
    const unsigned short* W = Wb + (size_t)blockIdx.z * EDIM * SLICE;
    float* C = out + (size_t)blockIdx.z * M * EDIM;

    int tid = threadIdx.x;
    int bm = blockIdx.y * 128;
    int bn = blockIdx.x * 128;
    int l = tid & 63;
    int w = tid >> 6;
    int wr = w >> 1, wc = w & 1;  // 2x2 wave grid
    int lane16 = l & 15, kq = l >> 4;

    // per-lane fragment base pointers (A: row=m, B: row=n; k-offset kq*8)
    const unsigned short* aptr[4];
    const unsigned short* bptr[4];
#pragma unroll
    for (int i = 0; i < 4; ++i) {
        int m = bm + wr * 64 + i * 16 + lane16;
        if (m >= M) m = M - 1;  // clamp (stores are guarded)
        aptr[i] = Ag + (size_t)m * SLICE + kq * 8;
        int n = bn + wc * 64 + i * 16 + lane16;
        bptr[i] = W + (size_t)n * SLICE + kq * 8;
    }

    f32x4 acc[4][4] = {};
    bf16x8 a0[4], b0[4], a1[4], b1[4];
#pragma unroll
    for (int i = 0; i < 4; ++i) {
        a0[i] = *(const bf16x8*)(aptr[i]);
        b0[i] = *(const bf16x8*)(bptr[i]);
    }

#pragma unroll
    for (int k0 = 32; k0 <= SLICE; k0 += 32) {
        if (k0 < SLICE) {
#pragma unroll
            for (int i = 0; i < 4; ++i) {
                a1[i] = *(const bf16x8*)(aptr[i] + k0);
                b1[i] = *(const bf16x8*)(bptr[i] + k0);
            }
        }
#pragma unroll
        for (int i = 0; i < 4; ++i)
#pragma unroll
            for (int j = 0; j < 4; ++j)
                acc[i][j] = __builtin_amdgcn_mfma_f32_16x16x32_bf16(a0[i], b0[j], acc[i][j], 0, 0, 0);
#pragma unroll
        for (int i = 0; i < 4; ++i) { a0[i] = a1[i]; b0[i] = b1[i]; }
    }

    // D mapping: row m = (l>>4)*4 + reg, col n = l&15
#pragma unroll
    for (int i = 0; i < 4; ++i) {
        int m0 = bm + wr * 64 + i * 16 + kq * 4;
#pragma unroll
        for (int j = 0; j < 4; ++j) {
            int n = bn + wc * 64 + j * 16 + lane16;
            f32x4 v = acc[i][j];
#pragma unroll
            for (int r = 0; r < 4; ++r) {
                int m = m0 + r;
                if (m < M) C[(size_t)m * EDIM + n] = v[r];
            }
        }
    }
}

// ---------------------------------------------------------------------------
// 4) pentachoron projections: dirs cached in registers (80 VGPR/lane),
//    16 rows per wave, shuffle reduce, no LDS, no barriers.
// ---------------------------------------------------------------------------
__global__ __launch_bounds__(256) void proj_kernel(const float* __restrict__ qkv,
                                                   const float* __restrict__ dirs,
                                                   float* __restrict__ outp, int M) {
    int t = threadIdx.x;
    int l = t & 63;
    int wv = t >> 6;

    float4 d[5][4];
#pragma unroll
    for (int v5 = 0; v5 < 5; ++v5)
#pragma unroll
        for (int it = 0; it < 4; ++it)
            d[v5][it] = ((const float4*)dirs)[v5 * 256 + it * 64 + l];

    int row0 = (blockIdx.x * 4 + wv) * 16;
    int total = 3 * M;
#pragma unroll 1
    for (int rr = 0; rr < 16; ++rr) {
        int r = row0 + rr;
        if (r >= total) return;  // uniform across wave
        const float4* row = (const float4*)(qkv + (size_t)r * EDIM);
        float acc5[5] = {0.f, 0.f, 0.f, 0.f, 0.f};
#pragma unroll
        for (int it = 0; it < 4; ++it) {
            float4 v = row[it * 64 + l];
#pragma unroll
            for (int v5 = 0; v5 < 5; ++v5) {
                acc5[v5] += v.x * d[v5][it].x + v.y * d[v5][it].y +
                            v.z * d[v5][it].z + v.w * d[v5][it].w;
            }
        }
        int q = r / M;
        int m = r - q * M;
#pragma unroll
        for (int v5 = 0; v5 < 5; ++v5) {
            float a = acc5[v5];
            for (int off = 32; off > 0; off >>= 1) a += __shfl_down(a, off, 64);
            if (l == 0) outp[(size_t)(q * 5 + v5) * M + m] = a;
        }
    }
}

// ---------------------------------------------------------------------------
extern "C" void kernel_launch(void* const* d_in, const int* in_sizes, int n_in,
                              void* d_out, int out_size, void* d_ws, size_t ws_size,
                              hipStream_t stream) {
    const float* tokens = (const float*)d_in[0];
    const float* fp     = (const float*)d_in[1];
    const float* Wg1    = (const float*)d_in[2];
    const float* bg1    = (const float*)d_in[3];
    const float* Wg2    = (const float*)d_in[4];
    const float* bg2    = (const float*)d_in[5];
    const float* alpha  = (const float*)d_in[6];
    const float* Wq     = (const float*)d_in[7];
    const float* Wk     = (const float*)d_in[8];
    const float* Wv     = (const float*)d_in[9];
    const float* penta  = (const float*)d_in[10];
    float* out = (float*)d_out;

    int Ntok = out_size / 12348;
    int M = BDIM * Ntok;

    char* ws = (char*)d_ws;
    int*            idx  = (int*)ws;
    unsigned short* Ag   = (unsigned short*)(ws + (32 << 10));
    unsigned short* Wb   = (unsigned short*)(ws + (8 << 20));
    float*          dirs = (float*)(ws + (12 << 20));

    prep_kernel<<<390, 1024, 0, stream>>>(fp, idx, penta, dirs, Wq, Wk, Wv, Wb);
    gate_kernel<<<(M + GT - 1) / GT, 256, 0, stream>>>(tokens, idx, Wg1, bg1, Wg2, bg2,
                                                       alpha, Ag, Ntok, M);

    dim3 gg(EDIM / 128, (M + 127) / 128, 3);
    qkv_mfma<<<gg, 256, 0, stream>>>(Ag, Wb, out, M);

    proj_kernel<<<(3 * M + 63) / 64, 256, 0, stream>>>(out, dirs, out + (size_t)3 * M * EDIM, M);
}